// Round 1
// baseline (10399.010 us; speedup 1.0000x reference)
//
#include <hip/hip_runtime.h>
#include <hip/hip_bf16.h>

#define BNH 32
#define L 1024
#define D 64
#define RP 129
#define CLIPV 64
#define TI 16
#define TJ 64
#define NT 256

// ---------------- Kernel 1: qe[b,i,r] = dot(q[b,i,:], emb_k[r,:]) ----------------
// Written into the p-region of d_out as scratch (p[b,i,0:129]); the main kernel
// reads its own rows' qe at block start, then overwrites with the real p.
__global__ __launch_bounds__(NT) void qe_kernel(const float* __restrict__ q,
                                                const float* __restrict__ emb_k,
                                                float* __restrict__ p_out) {
    __shared__ float e_s[RP][68];
    __shared__ float q_s[8][68];
    const int tid = threadIdx.x;
    const int b = blockIdx.x >> 7;          // 128 row-blocks per b (8 rows each)
    const int i0 = (blockIdx.x & 127) * 8;

    for (int t = tid; t < RP * 16; t += NT) {
        int r = t >> 4, c4 = t & 15;
        *reinterpret_cast<float4*>(&e_s[r][c4 * 4]) =
            *reinterpret_cast<const float4*>(emb_k + r * D + c4 * 4);
    }
    for (int t = tid; t < 8 * 16; t += NT) {
        int row = t >> 4, c4 = t & 15;
        *reinterpret_cast<float4*>(&q_s[row][c4 * 4]) =
            *reinterpret_cast<const float4*>(q + ((size_t)(b * L + i0 + row)) * D + c4 * 4);
    }
    __syncthreads();

    const int row = tid >> 5;   // 0..7
    const int rr = tid & 31;
    for (int r = rr; r < RP; r += 32) {
        float acc = 0.f;
#pragma unroll
        for (int d4 = 0; d4 < 16; ++d4) {
            float4 qv = *reinterpret_cast<const float4*>(&q_s[row][d4 * 4]);
            float4 ev = *reinterpret_cast<const float4*>(&e_s[r][d4 * 4]);
            acc += qv.x * ev.x + qv.y * ev.y + qv.z * ev.z + qv.w * ev.w;
        }
        p_out[((size_t)(b * L + i0 + row)) * L + r] = acc;
    }
}

// ---------------- Kernel 2: fused scores + softmax + p + PV + rel-pos value ----------------
__global__ __launch_bounds__(NT, 2) void attn_kernel(
    const float* __restrict__ q, const float* __restrict__ k, const float* __restrict__ v,
    const float* __restrict__ attn_w, const float* __restrict__ emb_v,
    const int* __restrict__ pos, const unsigned char* __restrict__ mask,
    float* __restrict__ out, float* __restrict__ p_out) {

    __shared__ float q_s[TI][68];
    __shared__ float kv_s[TJ][68];
    __shared__ float qe_s[TI][132];
    __shared__ float av_s[TI][132];
    __shared__ float p_s[TI][68];
    __shared__ int pos_s[L];

    const int tid = threadIdx.x;
    const int b = blockIdx.x >> 6;            // 64 row-tiles per b
    const int i0 = (blockIdx.x & 63) * TI;
    const int lane = tid & 63;
    const int w = tid >> 6;                   // wave 0..3
    const int rg = lane >> 4;                 // row group within wave
    const int ls = lane & 15;                 // lane within row group
    const int row = w * 4 + rg;               // 0..15
    const int gi = i0 + row;

    // ---- cooperative staging ----
    for (int t = tid; t < L / 4; t += NT)
        *reinterpret_cast<int4*>(&pos_s[t * 4]) =
            *reinterpret_cast<const int4*>(pos + b * L + t * 4);
    for (int t = tid; t < TI * 16; t += NT) {
        int rrow = t >> 4, c4 = t & 15;
        *reinterpret_cast<float4*>(&q_s[rrow][c4 * 4]) =
            *reinterpret_cast<const float4*>(q + ((size_t)(b * L + i0 + rrow)) * D + c4 * 4);
    }
    for (int t = tid; t < TI * 33; t += NT) {
        int rrow = t / 33, c4 = t % 33;
        const float* src = p_out + ((size_t)(b * L + i0 + rrow)) * L + c4 * 4;
        if (c4 < 32)
            *reinterpret_cast<float4*>(&qe_s[rrow][c4 * 4]) =
                *reinterpret_cast<const float4*>(src);
        else
            qe_s[rrow][128] = *src;
    }
    for (int t = tid; t < TI * 132; t += NT)
        (&av_s[0][0])[t] = 0.f;
    __syncthreads();

    const int pos_i = pos_s[gi];
    const size_t aw_row = ((size_t)(b * L + gi)) * L;
    float s[64];

    // ---- pass A: scores ----
#pragma unroll
    for (int jt = 0; jt < 16; ++jt) {
        const int j0 = jt * TJ;
        for (int t = tid; t < TJ * 16; t += NT) {
            int jrow = t >> 4, c4 = t & 15;
            *reinterpret_cast<float4*>(&kv_s[jrow][c4 * 4]) =
                *reinterpret_cast<const float4*>(k + ((size_t)(b * L + j0 + jrow)) * D + c4 * 4);
        }
        __syncthreads();
#pragma unroll
        for (int jl4 = 0; jl4 < 4; ++jl4) {
            const int jlocal = jl4 * 16 + ls;
            const int j = j0 + jlocal;
            float acc = 0.f;
#pragma unroll
            for (int d4 = 0; d4 < 16; ++d4) {
                float4 qv = *reinterpret_cast<const float4*>(&q_s[row][d4 * 4]);
                float4 kv = *reinterpret_cast<const float4*>(&kv_s[jlocal][d4 * 4]);
                acc += qv.x * kv.x + qv.y * kv.y + qv.z * kv.z + qv.w * kv.w;
            }
            int dd = pos_s[j] - pos_i;
            dd = min(max(dd, -CLIPV), CLIPV) + CLIPV;
            float sc = (acc + qe_s[row][dd] + attn_w[aw_row + j]) * 0.125f;
            if (mask[aw_row + j]) sc = -__builtin_inff();
            s[jt * 4 + jl4] = sc;
        }
        __syncthreads();
    }

    // ---- softmax over 64 regs x 16 lanes ----
    float m = -__builtin_inff();
#pragma unroll
    for (int jj = 0; jj < 64; ++jj) m = fmaxf(m, s[jj]);
#pragma unroll
    for (int off = 1; off < 16; off <<= 1) m = fmaxf(m, __shfl_xor(m, off, 64));
    float l = 0.f;
#pragma unroll
    for (int jj = 0; jj < 64; ++jj) { s[jj] = __expf(s[jj] - m); l += s[jj]; }
#pragma unroll
    for (int off = 1; off < 16; off <<= 1) l += __shfl_xor(l, off, 64);
    const float inv = 1.f / l;
#pragma unroll
    for (int jj = 0; jj < 64; ++jj) s[jj] *= inv;

    // ---- write p (overwrites qe scratch for these rows only) ----
    const size_t p_row = ((size_t)(b * L + gi)) * L;
#pragma unroll
    for (int jj = 0; jj < 64; ++jj) p_out[p_row + jj * 16 + ls] = s[jj];

    // ---- av scatter, run-length compressed (table monotone in j: pos sorted) ----
    {
        float accv = 0.f;
        int cur = -1;
#pragma unroll
        for (int jj = 0; jj < 64; ++jj) {
            const int j = jj * 16 + ls;
            int dd = pos_s[j] - pos_i;
            dd = min(max(dd, -CLIPV), CLIPV) + CLIPV;
            if (dd != cur) {
                if (cur >= 0) atomicAdd(&av_s[row][cur], accv);
                cur = dd;
                accv = 0.f;
            }
            accv += s[jj];
        }
        atomicAdd(&av_s[row][cur], accv);
    }

    // ---- pass B: out = p @ v ----
    float4 oacc = {0.f, 0.f, 0.f, 0.f};
#pragma unroll
    for (int jt = 0; jt < 16; ++jt) {
        const int j0 = jt * TJ;
        for (int t = tid; t < TJ * 16; t += NT) {
            int jrow = t >> 4, c4 = t & 15;
            *reinterpret_cast<float4*>(&kv_s[jrow][c4 * 4]) =
                *reinterpret_cast<const float4*>(v + ((size_t)(b * L + j0 + jrow)) * D + c4 * 4);
        }
#pragma unroll
        for (int jl4 = 0; jl4 < 4; ++jl4) p_s[row][jl4 * 16 + ls] = s[jt * 4 + jl4];
        __syncthreads();
#pragma unroll
        for (int jl = 0; jl < TJ; ++jl) {
            const float pv = p_s[row][jl];
            const float4 vv = *reinterpret_cast<const float4*>(&kv_s[jl][ls * 4]);
            oacc.x += pv * vv.x; oacc.y += pv * vv.y;
            oacc.z += pv * vv.z; oacc.w += pv * vv.w;
        }
        __syncthreads();
    }

    // ---- epilogue: out += av @ emb_v ----
    for (int r = 0; r < RP; ++r) {
        const float a = av_s[row][r];
        if (a != 0.f) {
            const float4 ev = *reinterpret_cast<const float4*>(emb_v + r * D + ls * 4);
            oacc.x += a * ev.x; oacc.y += a * ev.y;
            oacc.z += a * ev.z; oacc.w += a * ev.w;
        }
    }
    *reinterpret_cast<float4*>(out + ((size_t)(b * L + gi)) * D + ls * 4) = oacc;
}

extern "C" void kernel_launch(void* const* d_in, const int* in_sizes, int n_in,
                              void* d_out, int out_size, void* d_ws, size_t ws_size,
                              hipStream_t stream) {
    const float* q = (const float*)d_in[0];
    const float* k = (const float*)d_in[1];
    const float* v = (const float*)d_in[2];
    const float* attn_w = (const float*)d_in[3];
    const float* emb_k = (const float*)d_in[4];
    const float* emb_v = (const float*)d_in[5];
    const int* pos = (const int*)d_in[6];
    const unsigned char* mask = (const unsigned char*)d_in[7];
    float* out = (float*)d_out;
    float* p_out = out + (size_t)BNH * L * D;   // p region of d_out

    qe_kernel<<<BNH * (L / 8), NT, 0, stream>>>(q, emb_k, p_out);
    attn_kernel<<<BNH * (L / TI), NT, 0, stream>>>(q, k, v, attn_w, emb_v, pos, mask,
                                                   out, p_out);
}

// Round 2
// 624.735 us; speedup vs baseline: 16.6455x; 16.6455x over previous
//
#include <hip/hip_runtime.h>
#include <hip/hip_bf16.h>

#define BNH 32
#define L 1024
#define D 64
#define RP 129
#define CLIPV 64
#define TI 16
#define TJ 256
#define NT 256

typedef __attribute__((ext_vector_type(8))) short bf16x8;
typedef __attribute__((ext_vector_type(4))) float f32x4;

__device__ __forceinline__ unsigned short f2bf(float f) {
    unsigned int u = __builtin_bit_cast(unsigned int, f);
    return (unsigned short)((u + 0x7fffu + ((u >> 16) & 1u)) >> 16);
}

// ---------------- Kernel 1: qe[b,i,r] = dot(q[b,i,:], emb_k[r,:]) (fp32) ----------------
// Written into the p-region of d_out as scratch (p[b,i,0:129]); the main kernel
// stages its own rows' qe into LDS before overwriting the region with raw scores.
__global__ __launch_bounds__(NT) void qe_kernel(const float* __restrict__ q,
                                                const float* __restrict__ emb_k,
                                                float* __restrict__ p_out) {
    __shared__ float e_s[RP][68];
    __shared__ float q_s[8][68];
    const int tid = threadIdx.x;
    const int b = blockIdx.x >> 7;
    const int i0 = (blockIdx.x & 127) * 8;

    for (int t = tid; t < RP * 16; t += NT) {
        int r = t >> 4, c4 = t & 15;
        *reinterpret_cast<float4*>(&e_s[r][c4 * 4]) =
            *reinterpret_cast<const float4*>(emb_k + r * D + c4 * 4);
    }
    for (int t = tid; t < 8 * 16; t += NT) {
        int row = t >> 4, c4 = t & 15;
        *reinterpret_cast<float4*>(&q_s[row][c4 * 4]) =
            *reinterpret_cast<const float4*>(q + ((size_t)(b * L + i0 + row)) * D + c4 * 4);
    }
    __syncthreads();

    const int row = tid >> 5;
    const int rr = tid & 31;
    for (int r = rr; r < RP; r += 32) {
        float acc = 0.f;
#pragma unroll
        for (int d4 = 0; d4 < 16; ++d4) {
            float4 qv = *reinterpret_cast<const float4*>(&q_s[row][d4 * 4]);
            float4 ev = *reinterpret_cast<const float4*>(&e_s[r][d4 * 4]);
            acc += qv.x * ev.x + qv.y * ev.y + qv.z * ev.z + qv.w * ev.w;
        }
        p_out[((size_t)(b * L + i0 + row)) * L + r] = acc;
    }
}

// ---------------- Kernel 2: MFMA attention ----------------
// Pass A: raw scores (bf16 MFMA QK^T + qe + attn_w, /8, mask) -> p region; track row max.
// Pass B1: read raw scores, e=exp(s-m): accumulate l, av scatter, PV via MFMA (V^T in LDS).
// Pass B2: normalize p in place. Epilogue: out = (PV + av@emb_v) * inv_l.
__global__ __launch_bounds__(NT, 2) void attn_kernel(
    const float* __restrict__ q, const float* __restrict__ k, const float* __restrict__ v,
    const float* __restrict__ attn_w, const float* __restrict__ emb_v,
    const int* __restrict__ pos, const unsigned char* __restrict__ mask,
    float* __restrict__ out, float* __restrict__ p_out) {

    __shared__ __attribute__((aligned(16))) unsigned short kv_u[TJ * 72]; // k tile / vT tile(64x264)
    __shared__ __attribute__((aligned(16))) unsigned short q_u[TI * 72];
    __shared__ unsigned short pos_s[L];
    __shared__ float qe_s[TI * RP];
    __shared__ float av_s[TI * RP];
    __shared__ float out_s[TI * 68];
    __shared__ float m_part[4][16];
    __shared__ float m_s[16];
    __shared__ float l_s[16];

    const int tid = threadIdx.x;
    const int b = blockIdx.x >> 6;
    const int i0 = (blockIdx.x & 63) * TI;
    const int w = tid >> 6;          // wave 0..3 (owns cols [w*64, w*64+64) of each jt tile)
    const int lane = tid & 63;
    const int quad = lane >> 4;
    const int lo = lane & 15;

    // ---- init staging ----
    for (int t = tid; t < L; t += NT) pos_s[t] = (unsigned short)pos[b * L + t];
    if (tid < TI * 8) {
        int r = tid >> 3, dc = tid & 7;
        const float* src = q + ((size_t)(b * L + i0 + r)) * D + dc * 8;
        float4 f0 = *(const float4*)src;
        float4 f1 = *(const float4*)(src + 4);
        bf16x8 qq;
        qq[0] = (short)f2bf(f0.x); qq[1] = (short)f2bf(f0.y);
        qq[2] = (short)f2bf(f0.z); qq[3] = (short)f2bf(f0.w);
        qq[4] = (short)f2bf(f1.x); qq[5] = (short)f2bf(f1.y);
        qq[6] = (short)f2bf(f1.z); qq[7] = (short)f2bf(f1.w);
        *(bf16x8*)&q_u[r * 72 + dc * 8] = qq;
    }
    for (int t = tid; t < TI * RP; t += NT) {
        int r = t / RP, c = t - r * RP;
        qe_s[t] = p_out[((size_t)(b * L + i0 + r)) * L + c];
        av_s[t] = 0.f;
    }
    for (int t = tid; t < TI * 68; t += NT) out_s[t] = 0.f;
    if (tid < 16) l_s[tid] = 0.f;
    __syncthreads();

    // q A-frags: lane supplies A row m = lo, k-chunk = kc*32 + quad*8
    const bf16x8 aq0 = *(const bf16x8*)&q_u[lo * 72 + quad * 8];
    const bf16x8 aq1 = *(const bf16x8*)&q_u[lo * 72 + 32 + quad * 8];

    int posA[4];   // pos of this lane's C/D rows (quad*4+r)
#pragma unroll
    for (int r = 0; r < 4; ++r) posA[r] = (int)pos_s[i0 + quad * 4 + r];

    // ---- pass A: raw scores -> global, track row max ----
    float mA[4] = {-3e38f, -3e38f, -3e38f, -3e38f};
    for (int jt = 0; jt < 4; ++jt) {
        const int j0 = jt * TJ;
#pragma unroll
        for (int s = 0; s < 8; ++s) {   // stage 256x64 k tile as bf16
            int ch = s * NT + tid;
            int col = ch >> 3, dc = ch & 7;
            const float* src = k + ((size_t)(b * L + j0 + col)) * D + dc * 8;
            float4 f0 = *(const float4*)src;
            float4 f1 = *(const float4*)(src + 4);
            bf16x8 kk;
            kk[0] = (short)f2bf(f0.x); kk[1] = (short)f2bf(f0.y);
            kk[2] = (short)f2bf(f0.z); kk[3] = (short)f2bf(f0.w);
            kk[4] = (short)f2bf(f1.x); kk[5] = (short)f2bf(f1.y);
            kk[6] = (short)f2bf(f1.z); kk[7] = (short)f2bf(f1.w);
            *(bf16x8*)&kv_u[col * 72 + dc * 8] = kk;
        }
        __syncthreads();
#pragma unroll
        for (int ct = 0; ct < 4; ++ct) {
            const int ncol = w * 64 + ct * 16 + lo;   // local col; B-frag col n = lo
            const int j = j0 + ncol;
            bf16x8 b0 = *(const bf16x8*)&kv_u[ncol * 72 + quad * 8];
            bf16x8 b1 = *(const bf16x8*)&kv_u[ncol * 72 + 32 + quad * 8];
            f32x4 acc = {0.f, 0.f, 0.f, 0.f};
            acc = __builtin_amdgcn_mfma_f32_16x16x32_bf16(aq0, b0, acc, 0, 0, 0);
            acc = __builtin_amdgcn_mfma_f32_16x16x32_bf16(aq1, b1, acc, 0, 0, 0);
            const int pj = (int)pos_s[j];
#pragma unroll
            for (int r = 0; r < 4; ++r) {
                const int row = quad * 4 + r;         // C/D row = quad*4 + reg
                const size_t grow = (size_t)(b * L + i0 + row) * L + j;
                int dd = pj - posA[r];
                dd = min(max(dd, -CLIPV), CLIPV) + CLIPV;
                float sc = (acc[r] + qe_s[row * RP + dd] + attn_w[grow]) * 0.125f;
                if (mask[grow]) sc = -3e38f;
                mA[r] = fmaxf(mA[r], sc);
                p_out[grow] = sc;
            }
        }
        __syncthreads();
    }

    // ---- row-max reduction ----
#pragma unroll
    for (int off = 1; off < 16; off <<= 1) {
#pragma unroll
        for (int r = 0; r < 4; ++r) mA[r] = fmaxf(mA[r], __shfl_xor(mA[r], off, 64));
    }
    if (lo == 0) {
#pragma unroll
        for (int r = 0; r < 4; ++r) m_part[w][quad * 4 + r] = mA[r];
    }
    __syncthreads();
    if (tid < 16)
        m_s[tid] = fmaxf(fmaxf(m_part[0][tid], m_part[1][tid]),
                         fmaxf(m_part[2][tid], m_part[3][tid]));
    __syncthreads();

    // ---- pass B1: e = exp(s-m); l, av, PV ----
    const float mrow = m_s[lo];              // A row m = lo
    const int pos_m = (int)pos_s[i0 + lo];
    float l_r = 0.f;
    f32x4 oc[4];
#pragma unroll
    for (int ct = 0; ct < 4; ++ct) { oc[ct][0]=0.f; oc[ct][1]=0.f; oc[ct][2]=0.f; oc[ct][3]=0.f; }

    for (int jt = 0; jt < 4; ++jt) {
        const int j0 = jt * TJ;
        __syncthreads();
        {   // stage V^T tile: vT[d][col] bf16, stride 264
            const float* src = v + ((size_t)(b * L + j0 + tid)) * D;
#pragma unroll
            for (int s = 0; s < 16; ++s) {
                float4 f = *(const float4*)(src + s * 4);
                kv_u[(s * 4 + 0) * 264 + tid] = f2bf(f.x);
                kv_u[(s * 4 + 1) * 264 + tid] = f2bf(f.y);
                kv_u[(s * 4 + 2) * 264 + tid] = f2bf(f.z);
                kv_u[(s * 4 + 3) * 264 + tid] = f2bf(f.w);
            }
        }
        __syncthreads();

        bf16x8 af[2];
#pragma unroll
        for (int kc = 0; kc < 2; ++kc) {
            const int bcol = j0 + w * 64 + kc * 32 + quad * 8;
            const float* sp = p_out + (size_t)(b * L + i0 + lo) * L + bcol;
            float4 s0 = *(const float4*)sp;
            float4 s1 = *(const float4*)(sp + 4);
            float ev[8];
            ev[0] = __expf(s0.x - mrow); ev[1] = __expf(s0.y - mrow);
            ev[2] = __expf(s0.z - mrow); ev[3] = __expf(s0.w - mrow);
            ev[4] = __expf(s1.x - mrow); ev[5] = __expf(s1.y - mrow);
            ev[6] = __expf(s1.z - mrow); ev[7] = __expf(s1.w - mrow);
            l_r += ev[0] + ev[1] + ev[2] + ev[3] + ev[4] + ev[5] + ev[6] + ev[7];
            // av scatter: run-length compressed (pos sorted => dd monotone in j)
            int cur = -1; float a = 0.f;
#pragma unroll
            for (int i = 0; i < 8; ++i) {
                int dd = (int)pos_s[bcol + i] - pos_m;
                dd = min(max(dd, -CLIPV), CLIPV) + CLIPV;
                if (dd != cur) {
                    if (cur >= 0) atomicAdd(&av_s[lo * RP + cur], a);
                    cur = dd; a = 0.f;
                }
                a += ev[i];
            }
            atomicAdd(&av_s[lo * RP + cur], a);
            bf16x8 f;
#pragma unroll
            for (int i = 0; i < 8; ++i) f[i] = (short)f2bf(ev[i]);
            af[kc] = f;
        }
#pragma unroll
        for (int ct = 0; ct < 4; ++ct) {
#pragma unroll
            for (int kc = 0; kc < 2; ++kc) {
                bf16x8 bf = *(const bf16x8*)
                    &kv_u[(ct * 16 + lo) * 264 + w * 64 + kc * 32 + quad * 8];
                oc[ct] = __builtin_amdgcn_mfma_f32_16x16x32_bf16(af[kc], bf, oc[ct], 0, 0, 0);
            }
        }
    }

    // unnormalized PV partials -> out_s; l -> l_s
#pragma unroll
    for (int ct = 0; ct < 4; ++ct) {
#pragma unroll
        for (int r = 0; r < 4; ++r)
            atomicAdd(&out_s[(quad * 4 + r) * 68 + ct * 16 + lo], oc[ct][r]);
    }
    l_r += __shfl_xor(l_r, 16, 64);
    l_r += __shfl_xor(l_r, 32, 64);
    if (lane < 16) atomicAdd(&l_s[lo], l_r);
    __syncthreads();
    if (tid < 16) l_s[tid] = 1.f / l_s[tid];
    __syncthreads();

    // ---- pass B2: normalize p in place ----
#pragma unroll
    for (int s = 0; s < 16; ++s) {
        int idx = s * NT + tid;
        int row = idx >> 8, c4 = idx & 255;
        float* addr = p_out + (size_t)(b * L + i0 + row) * L + c4 * 4;
        float4 sv = *(float4*)addr;
        const float mm = m_s[row], il = l_s[row];
        float4 pv;
        pv.x = __expf(sv.x - mm) * il;
        pv.y = __expf(sv.y - mm) * il;
        pv.z = __expf(sv.z - mm) * il;
        pv.w = __expf(sv.w - mm) * il;
        *(float4*)addr = pv;
    }

    // ---- epilogue: out = (PV + av @ emb_v) * inv_l ----
    {
        const int row = tid >> 4, dc = tid & 15;
        float4 o = *(const float4*)&out_s[row * 68 + dc * 4];
        const float il = l_s[row];
        for (int r = 0; r < RP; ++r) {
            float a = av_s[row * RP + r];
            if (a != 0.f) {
                const float4 ev4 = *(const float4*)(emb_v + r * D + dc * 4);
                o.x += a * ev4.x; o.y += a * ev4.y;
                o.z += a * ev4.z; o.w += a * ev4.w;
            }
        }
        o.x *= il; o.y *= il; o.z *= il; o.w *= il;
        *(float4*)(out + (size_t)(b * L + i0 + row) * D + dc * 4) = o;
    }
}

extern "C" void kernel_launch(void* const* d_in, const int* in_sizes, int n_in,
                              void* d_out, int out_size, void* d_ws, size_t ws_size,
                              hipStream_t stream) {
    const float* q = (const float*)d_in[0];
    const float* k = (const float*)d_in[1];
    const float* v = (const float*)d_in[2];
    const float* attn_w = (const float*)d_in[3];
    const float* emb_k = (const float*)d_in[4];
    const float* emb_v = (const float*)d_in[5];
    const int* pos = (const int*)d_in[6];
    const unsigned char* mask = (const unsigned char*)d_in[7];
    float* out = (float*)d_out;
    float* p_out = out + (size_t)BNH * L * D;   // p region of d_out

    qe_kernel<<<BNH * (L / 8), NT, 0, stream>>>(q, emb_k, p_out);
    attn_kernel<<<BNH * (L / TI), NT, 0, stream>>>(q, k, v, attn_w, emb_v, pos, mask,
                                                   out, p_out);
}